// Round 8
// baseline (115.133 us; speedup 1.0000x reference)
//
#include <hip/hip_runtime.h>
#include <hip/hip_fp16.h>

#define N_NODES 50000
#define D_IN    128
#define D_OUT   64
#define N_EDGES 800000
#define NTILES  3125          // 50000/16 exact
#define GEMM_BLOCKS 256
#define RP_BLOCKS   196       // ceil(50001/256)
#define GEMM_WAVES  (GEMM_BLOCKS * 4)

typedef _Float16 f16x8 __attribute__((ext_vector_type(8)));
typedef float    f32x4 __attribute__((ext_vector_type(4)));

// ---------------------------------------------------------------------------
// Kernel A: fused  X' = X@W (MFMA fp16, hi/lo-split A, fp32 acc)  +  rowptr.
// R5 post-mortem: one-tile-per-wave version ran 32us (vs ~6us roofline) —
// latency-structured (stage W -> sync -> 8 dependent A loads -> 32 MFMA ->
// exit; W re-staged per 782 blocks). v6: 1024 waves grid-stride ~3 tiles
// each; B-frags persist in VGPRs across tiles; next tile's A prefetched
// before current MFMAs -> HBM latency hidden under compute.
// Blocks >= GEMM_BLOCKS run the independent rowptr binary search (fused to
// drop one dispatch; runs concurrently on otherwise-idle CUs).
// Fragment maps verified by R5 pass: A[m=lane&15][k=(lane>>4)*8+j+32ks],
// D row=(lane>>4)*4+r col=ct*16+(lane&15).
// ---------------------------------------------------------------------------
__global__ __launch_bounds__(256) void gemm_rowptr(const float* __restrict__ X,
                                                   const float* __restrict__ W,
                                                   const int* __restrict__ row,
                                                   _Float16* __restrict__ Xp,
                                                   int* __restrict__ rowptr) {
    const int tid = threadIdx.x;

    if (blockIdx.x >= GEMM_BLOCKS) {           // ---- rowptr part ----
        const int i = (blockIdx.x - GEMM_BLOCKS) * 256 + tid;
        if (i <= N_NODES) {
            int lo = 0, hi = N_EDGES;
            while (lo < hi) {
                int mid = (lo + hi) >> 1;
                if (row[mid] < i) lo = mid + 1; else hi = mid;
            }
            rowptr[i] = lo;
        }
        return;
    }

    // ---- gemm part ----
    // B-fragments pre-arranged: frag f=ct*4+ks, lane l, elem j at Bf[(f*64+l)*8+j]
    __shared__ _Float16 Bf[16 * 64 * 8];   // 16 KB
    #pragma unroll
    for (int i2 = 0; i2 < 4; ++i2) {
        const int p  = tid + 256 * i2;     // 0..1023
        const int l  = p & 63;
        const int f  = p >> 6;
        const int ct = f >> 2, ks = f & 3;
        const int krow = ks * 32 + (l >> 4) * 8;
        const int c    = ct * 16 + (l & 15);
        f16x8 tmp;
        #pragma unroll
        for (int j = 0; j < 8; ++j) tmp[j] = (_Float16)W[(krow + j) * D_OUT + c];
        *reinterpret_cast<f16x8*>(&Bf[p * 8]) = tmp;
    }
    __syncthreads();

    const int wave = (blockIdx.x * 256 + tid) >> 6;  // 0..1023
    const int lane = tid & 63;
    const int g    = lane >> 4;    // 0..3
    const int lm   = lane & 15;    // 0..15

    // all 16 B-fragments -> registers, persist across the tile loop
    f16x8 bf[16];
    #pragma unroll
    for (int f = 0; f < 16; ++f)
        bf[f] = *reinterpret_cast<const f16x8*>(&Bf[(f * 64 + lane) * 8]);

    const float4* X4 = reinterpret_cast<const float4*>(X);

    // prime A for first tile
    int t = wave;
    float4 xa[8];
    if (t < NTILES) {
        const float4* Xr = X4 + (size_t)(t * 16 + lm) * 32;
        #pragma unroll
        for (int ks = 0; ks < 4; ++ks) {
            xa[2 * ks]     = Xr[ks * 8 + g * 2];
            xa[2 * ks + 1] = Xr[ks * 8 + g * 2 + 1];
        }
    }

    while (t < NTILES) {
        // prefetch next tile's A before this tile's MFMAs (latency hides)
        const int tn = t + GEMM_WAVES;
        float4 xb[8];
        if (tn < NTILES) {
            const float4* Xr = X4 + (size_t)(tn * 16 + lm) * 32;
            #pragma unroll
            for (int ks = 0; ks < 4; ++ks) {
                xb[2 * ks]     = Xr[ks * 8 + g * 2];
                xb[2 * ks + 1] = Xr[ks * 8 + g * 2 + 1];
            }
        }

        f32x4 acc[4];
        #pragma unroll
        for (int ct = 0; ct < 4; ++ct) acc[ct] = (f32x4){0.f, 0.f, 0.f, 0.f};

        #pragma unroll
        for (int ks = 0; ks < 4; ++ks) {
            const float xf0 = xa[2*ks].x, xf1 = xa[2*ks].y, xf2 = xa[2*ks].z, xf3 = xa[2*ks].w;
            const float xf4 = xa[2*ks+1].x, xf5 = xa[2*ks+1].y, xf6 = xa[2*ks+1].z, xf7 = xa[2*ks+1].w;
            f16x8 ahi, alo;
            ahi[0] = (_Float16)xf0; alo[0] = (_Float16)(xf0 - (float)ahi[0]);
            ahi[1] = (_Float16)xf1; alo[1] = (_Float16)(xf1 - (float)ahi[1]);
            ahi[2] = (_Float16)xf2; alo[2] = (_Float16)(xf2 - (float)ahi[2]);
            ahi[3] = (_Float16)xf3; alo[3] = (_Float16)(xf3 - (float)ahi[3]);
            ahi[4] = (_Float16)xf4; alo[4] = (_Float16)(xf4 - (float)ahi[4]);
            ahi[5] = (_Float16)xf5; alo[5] = (_Float16)(xf5 - (float)ahi[5]);
            ahi[6] = (_Float16)xf6; alo[6] = (_Float16)(xf6 - (float)ahi[6]);
            ahi[7] = (_Float16)xf7; alo[7] = (_Float16)(xf7 - (float)ahi[7]);
            #pragma unroll
            for (int ct = 0; ct < 4; ++ct) {
                acc[ct] = __builtin_amdgcn_mfma_f32_16x16x32_f16(ahi, bf[ct * 4 + ks], acc[ct], 0, 0, 0);
                acc[ct] = __builtin_amdgcn_mfma_f32_16x16x32_f16(alo, bf[ct * 4 + ks], acc[ct], 0, 0, 0);
            }
        }

        // store D: row = g*4+r, col = ct*16+lm (lanes 0-15 form 32B runs)
        #pragma unroll
        for (int ct = 0; ct < 4; ++ct)
            #pragma unroll
            for (int r = 0; r < 4; ++r)
                Xp[(size_t)(t * 16 + g * 4 + r) * D_OUT + ct * 16 + lm] = (_Float16)acc[ct][r];

        t = tn;
        #pragma unroll
        for (int q = 0; q < 8; ++q) xa[q] = xb[q];
    }
}

// ---------------------------------------------------------------------------
// Kernel B: out[i,:] = sum over edges of fp16 Xp[col[e],:].
// R5: agg ~23us vs ~8us L2/L3-BW floor -> partially issue/latency-bound.
// v6: one wave per row, lane-halves process alternate edges; each lane loads
// uint (=half2, 2 cols) -> VMEM instruction count halved at same transaction
// count; 8-deep batch per half = 16 edge-lines in flight per wave.
// __shfl_xor(32) combines halves; lanes 0-31 write float2 (256B coalesced).
// ---------------------------------------------------------------------------
__global__ __launch_bounds__(256) void aggregate(const __half* __restrict__ Xp,
                                                 const int* __restrict__ col,
                                                 const int* __restrict__ rowptr,
                                                 float* __restrict__ out) {
    const int wid  = (blockIdx.x * 256 + threadIdx.x) >> 6; // row id
    const int lane = threadIdx.x & 63;
    const int h    = lane >> 5;    // half id: even/odd edges
    const int c2   = lane & 31;    // uint index within row (cols 2c2, 2c2+1)

    const int lo = rowptr[wid];
    const int hi = rowptr[wid + 1];

    const uint* Xp32 = reinterpret_cast<const uint*>(Xp);  // row stride 32 uints
    float ax = 0.f, ay = 0.f;

    int e = lo + h;
    for (; e + 16 <= hi; e += 16) {   // 8 edges per half per batch
        int c[8];
        #pragma unroll
        for (int q = 0; q < 8; ++q) c[q] = col[e + 2 * q];
        uint u[8];
        #pragma unroll
        for (int q = 0; q < 8; ++q) u[q] = Xp32[(size_t)c[q] * 32 + c2];
        #pragma unroll
        for (int q = 0; q < 8; ++q) {
            const __half2 hv = *reinterpret_cast<const __half2*>(&u[q]);
            const float2  f  = __half22float2(hv);
            ax += f.x; ay += f.y;
        }
    }
    for (; e < hi; e += 2) {
        const uint u = Xp32[(size_t)col[e] * 32 + c2];
        const __half2 hv = *reinterpret_cast<const __half2*>(&u);
        const float2  f  = __half22float2(hv);
        ax += f.x; ay += f.y;
    }

    // combine even/odd halves (partner lane ^32 holds same cols)
    ax += __shfl_xor(ax, 32, 64);
    ay += __shfl_xor(ay, 32, 64);

    if (h == 0) {
        float2 v; v.x = ax; v.y = ay;
        *reinterpret_cast<float2*>(&out[(size_t)wid * D_OUT + c2 * 2]) = v;
    }
}

// ---------------------------------------------------------------------------
extern "C" void kernel_launch(void* const* d_in, const int* in_sizes, int n_in,
                              void* d_out, int out_size, void* d_ws, size_t ws_size,
                              hipStream_t stream) {
    const float* X   = (const float*)d_in[0];
    const float* W   = (const float*)d_in[1];
    const int*   row = (const int*)d_in[2];
    const int*   col = (const int*)d_in[3];
    float*       out = (float*)d_out;

    // workspace layout: Xp [50000*64 fp16 = 6.4MB] | rowptr [(N+1) i32]
    _Float16* Xp     = (_Float16*)d_ws;
    int*      rowptr = (int*)((char*)d_ws + (size_t)N_NODES * D_OUT * sizeof(_Float16));

    // fused gemm (blocks 0..255) + rowptr (blocks 256..451)
    hipLaunchKernelGGL(gemm_rowptr, dim3(GEMM_BLOCKS + RP_BLOCKS), dim3(256), 0, stream,
                       X, W, row, Xp, rowptr);
    // aggregation: one wave per row
    hipLaunchKernelGGL(aggregate, dim3((N_NODES * 64) / 256), dim3(256), 0, stream,
                       (const __half*)Xp, col, rowptr, out);
}